// Round 1
// baseline (1064.459 us; speedup 1.0000x reference)
//
#include <hip/hip_runtime.h>
#include <stdint.h>

#define L_LAYERS 4
#define BATCH 8
#define PHH 24
#define PWW 24
#define PP (PHH*PWW)        // 576
#define DD 1024
#define ROWS (BATCH*PP)     // 4608
#define OH 336
#define OW 336
#define NTILES 72           // 4608/64
#define MTILES 36           // 4608/128

typedef __attribute__((ext_vector_type(8))) __bf16 bf16x8;
typedef __attribute__((ext_vector_type(4))) float f32x4;

// float -> bf16 round-to-nearest-even (raw bits), avoids bf16 API differences
__device__ __forceinline__ unsigned short f2bf(float f) {
  unsigned int u = __float_as_uint(f);
  unsigned int r = (u + 0x7FFFu + ((u >> 16) & 1u)) >> 16;
  return (unsigned short)r;
}

// async global->LDS, 16B per lane. LDS dest must be wave-uniform base + lane*16.
__device__ __forceinline__ void async16(const void* g, void* l) {
  __builtin_amdgcn_global_load_lds(
      (const __attribute__((address_space(1))) void*)(size_t)(uintptr_t)g,
      (__attribute__((address_space(3))) void*)(uint32_t)(uintptr_t)l,
      16, 0, 0);
}

// ---------------------------------------------------------------------------
// Kernel 1: avg-pool (rxr, zero-pad, SAME) + L2-normalize + cast to bf16.
// Note: the /r^2 cancels under normalization, so we normalize the plain sum.
// One block per row (b,p); 256 threads x 4 floats = 1024 dims.
// ---------------------------------------------------------------------------
__global__ __launch_bounds__(256) void pool_norm_kernel(
    const float* __restrict__ feat,      // layer base: [BATCH][PP][DD]
    unsigned short* __restrict__ nf,     // [ROWS][DD] bf16 bits
    int r) {
  const int row = blockIdx.x;            // b*576 + p
  const int b = row / PP;
  const int p = row % PP;
  const int py = p / PWW, px = p % PWW;
  const int pad = r >> 1;
  const int t = threadIdx.x;
  const int d0 = t * 4;
  const float* base = feat + (size_t)b * PP * DD;

  float a0 = 0.f, a1 = 0.f, a2 = 0.f, a3 = 0.f;
  for (int dy = -pad; dy <= pad; ++dy) {
    int yy = py + dy; if (yy < 0 || yy >= PHH) continue;
    for (int dx = -pad; dx <= pad; ++dx) {
      int xx = px + dx; if (xx < 0 || xx >= PWW) continue;
      const float4 v = *(const float4*)(base + (size_t)(yy * PWW + xx) * DD + d0);
      a0 += v.x; a1 += v.y; a2 += v.z; a3 += v.w;
    }
  }
  float ss = a0*a0 + a1*a1 + a2*a2 + a3*a3;
  #pragma unroll
  for (int off = 32; off > 0; off >>= 1) ss += __shfl_down(ss, off);
  __shared__ float red[4];
  const int lane = t & 63, w = t >> 6;
  if (lane == 0) red[w] = ss;
  __syncthreads();
  const float tot = red[0] + red[1] + red[2] + red[3];
  const float rn = rsqrtf(tot);

  ushort4 o;
  o.x = f2bf(a0 * rn); o.y = f2bf(a1 * rn);
  o.z = f2bf(a2 * rn); o.w = f2bf(a3 * rn);
  *(ushort4*)(nf + (size_t)row * DD + d0) = o;
}

// ---------------------------------------------------------------------------
// Kernel 2: C = F * F^T tile (128 rows x 64 cols) over K=1024, fused row-max
// over the 64 cols (one 64-col tile = 1/9 of one image's 576 patches).
// 4 waves in 2x2 layout; MFMA 16x16x32 bf16; global_load_lds staging with
// XOR-swizzled LDS chunks (conflict-free ds_read_b128, no padding possible).
// partialL[row][ntile] = max over the 64 cols.
// ---------------------------------------------------------------------------
__global__ __launch_bounds__(256, 4) void gemm_max_kernel(
    const unsigned short* __restrict__ nf,   // [ROWS][DD] bf16 bits
    float* __restrict__ partialL) {          // [ROWS][NTILES]
  __shared__ unsigned short As[128 * 64];
  __shared__ unsigned short Bs[64 * 64];
  __shared__ float red[128][2];

  const int t = threadIdx.x;
  const int lane = t & 63;
  const int wave = t >> 6;
  const int wm = wave >> 1;    // row half (64 rows each)
  const int wn = wave & 1;     // col half (32 cols each)
  const int ntile = blockIdx.x;
  const int mtile = blockIdx.y;
  const int row0 = mtile * 128;
  const int col0 = ntile * 64;

  const f32x4 zero = {0.f, 0.f, 0.f, 0.f};
  f32x4 acc[4][2];
  #pragma unroll
  for (int m = 0; m < 4; ++m)
    #pragma unroll
    for (int n = 0; n < 2; ++n) acc[m][n] = zero;

  const unsigned short* gA = nf + (size_t)row0 * DD;
  const unsigned short* gB = nf + (size_t)col0 * DD;

  for (int kt = 0; kt < DD / 64; ++kt) {
    const int k0 = kt * 64;
    // stage A: 128x64 bf16 = 1024 16B-chunks; lane chunk c -> row=c/8, slot j=c%7
    // holds global k-chunk j ^ (row&7)  (XOR swizzle for conflict-free reads)
    #pragma unroll
    for (int i = 0; i < 4; ++i) {
      int c = i * 256 + t;
      int row = c >> 3, j = c & 7;
      int g = j ^ (row & 7);
      async16(gA + (size_t)row * DD + k0 + g * 8, &As[c * 8]);
    }
    #pragma unroll
    for (int i = 0; i < 2; ++i) {
      int c = i * 256 + t;
      int row = c >> 3, j = c & 7;
      int g = j ^ (row & 7);
      async16(gB + (size_t)row * DD + k0 + g * 8, &Bs[c * 8]);
    }
    __syncthreads();   // drains vmcnt (global_load_lds) + barrier
    #pragma unroll
    for (int s = 0; s < 2; ++s) {
      const int kc = s * 4 + (lane >> 4);   // 16B chunk index in the 64-wide K
      bf16x8 af[4], bfr[2];
      #pragma unroll
      for (int m = 0; m < 4; ++m) {
        int row = wm * 64 + m * 16 + (lane & 15);
        af[m] = *(const bf16x8*)&As[row * 64 + ((kc ^ (row & 7)) << 3)];
      }
      #pragma unroll
      for (int n = 0; n < 2; ++n) {
        int brow = wn * 32 + n * 16 + (lane & 15);
        bfr[n] = *(const bf16x8*)&Bs[brow * 64 + ((kc ^ (brow & 7)) << 3)];
      }
      #pragma unroll
      for (int m = 0; m < 4; ++m)
        #pragma unroll
        for (int n = 0; n < 2; ++n)
          acc[m][n] = __builtin_amdgcn_mfma_f32_16x16x32_bf16(af[m], bfr[n], acc[m][n], 0, 0, 0);
    }
    __syncthreads();
  }

  // Row-max over this block's 64 cols.
  // C/D layout: col = lane&15, row = (lane>>4)*4 + reg  [m89]
  float rmax[4][4];
  #pragma unroll
  for (int m = 0; m < 4; ++m) {
    #pragma unroll
    for (int g = 0; g < 4; ++g) {
      float v = fmaxf(acc[m][0][g], acc[m][1][g]);  // max over this wave's 2 col-frags
      v = fmaxf(v, __shfl_xor(v, 1));
      v = fmaxf(v, __shfl_xor(v, 2));
      v = fmaxf(v, __shfl_xor(v, 4));
      v = fmaxf(v, __shfl_xor(v, 8));               // max over 16 cols in frag
      rmax[m][g] = v;                               // valid in all lanes
    }
  }
  if ((lane & 15) == 0) {
    const int q = lane >> 4;
    #pragma unroll
    for (int m = 0; m < 4; ++m)
      #pragma unroll
      for (int g = 0; g < 4; ++g)
        red[wm * 64 + m * 16 + q * 4 + g][wn] = rmax[m][g];
  }
  __syncthreads();
  if (t < 128) {
    float v = fmaxf(red[t][0], red[t][1]);
    partialL[(size_t)(row0 + t) * NTILES + ntile] = v;
  }
}

// ---------------------------------------------------------------------------
// Kernel 3: per row: per layer, max over 9 q-tiles per image c, d-transform,
// top-2 smallest over c != b, accumulate into scores (summed over r and l).
// ---------------------------------------------------------------------------
__global__ __launch_bounds__(256) void reduce_topk_kernel(
    const float* __restrict__ partial,   // [L][ROWS][NTILES]
    float* __restrict__ scores) {        // [ROWS] accumulator
  const int row = blockIdx.x * 256 + threadIdx.x;
  if (row >= ROWS) return;
  const int b = row / PP;
  float sum = 0.f;
  for (int l = 0; l < L_LAYERS; ++l) {
    const float* pr = partial + ((size_t)l * ROWS + row) * NTILES;
    float d1 = 1e30f, d2 = 1e30f;
    #pragma unroll
    for (int c = 0; c < BATCH; ++c) {
      if (c == b) continue;
      float md = pr[c * 9];
      #pragma unroll
      for (int q = 1; q < 9; ++q) md = fmaxf(md, pr[c * 9 + q]);
      float d = sqrtf(fmaxf(2.f - 2.f * md, 0.f));
      if (d < d1) { d2 = d1; d1 = d; }
      else if (d < d2) { d2 = d; }
    }
    sum += 0.5f * (d1 + d2);
  }
  scores[row] += sum;
}

// ---------------------------------------------------------------------------
// Kernel 4: scores_image[b] = max_p scores[b,p] / 12
// ---------------------------------------------------------------------------
__global__ __launch_bounds__(256) void image_max_kernel(
    const float* __restrict__ scores, float* __restrict__ out) {
  const int b = blockIdx.x;
  const int t = threadIdx.x;
  float m = -1e30f;
  for (int p = t; p < PP; p += 256) m = fmaxf(m, scores[b * PP + p]);
  #pragma unroll
  for (int off = 32; off > 0; off >>= 1) m = fmaxf(m, __shfl_down(m, off));
  __shared__ float red[4];
  if ((t & 63) == 0) red[t >> 6] = m;
  __syncthreads();
  if (t == 0)
    out[b] = fmaxf(fmaxf(red[0], red[1]), fmaxf(red[2], red[3])) * (1.f / 12.f);
}

// ---------------------------------------------------------------------------
// Kernel 5: bilinear (align_corners) 24x24 -> 336x336, scale 1/12
// ---------------------------------------------------------------------------
__global__ __launch_bounds__(256) void upsample_kernel(
    const float* __restrict__ scores, float* __restrict__ out) {
  const int idx = blockIdx.x * 256 + threadIdx.x;
  if (idx >= BATCH * OH * OW) return;
  const int b = idx / (OH * OW);
  const int rem = idx % (OH * OW);
  const int y = rem / OW, x = rem % OW;
  const float sc = (float)(23.0 / 335.0);
  const float ys = y * sc, xs = x * sc;
  const int y0 = (int)floorf(ys), x0 = (int)floorf(xs);
  const float wy = ys - (float)y0, wx = xs - (float)x0;
  const int y1 = min(y0 + 1, PHH - 1), x1 = min(x0 + 1, PWW - 1);
  const float* sb = scores + b * PP;
  const float f00 = sb[y0 * PWW + x0], f01 = sb[y0 * PWW + x1];
  const float f10 = sb[y1 * PWW + x0], f11 = sb[y1 * PWW + x1];
  const float v = f00 * (1.f - wy) * (1.f - wx) + f01 * (1.f - wy) * wx +
                  f10 * wy * (1.f - wx) + f11 * wy * wx;
  out[8 + idx] = v * (1.f / 12.f);
}

// ---------------------------------------------------------------------------
extern "C" void kernel_launch(void* const* d_in, const int* in_sizes, int n_in,
                              void* d_out, int out_size, void* d_ws, size_t ws_size,
                              hipStream_t stream) {
  const float* feat = (const float*)d_in[0];     // [4][8][576][1024] f32
  float* out = (float*)d_out;                    // [8] ++ [8][336][336]
  char* ws = (char*)d_ws;

  // workspace layout (~14.8 MB)
  unsigned short* nf   = (unsigned short*)ws;                          // 9,437,184 B
  float*          part = (float*)(ws + 9437184);                       // 5,308,416 B
  float*          scr  = (float*)(ws + 9437184 + 5308416);             //    18,432 B

  hipMemsetAsync(scr, 0, ROWS * sizeof(float), stream);

  const int rlist[3] = {1, 3, 5};
  for (int ri = 0; ri < 3; ++ri) {
    const int r = rlist[ri];
    for (int l = 0; l < L_LAYERS; ++l) {
      pool_norm_kernel<<<ROWS, 256, 0, stream>>>(
          feat + (size_t)l * BATCH * PP * DD, nf, r);
      gemm_max_kernel<<<dim3(NTILES, MTILES), 256, 0, stream>>>(
          nf, part + (size_t)l * ROWS * NTILES);
    }
    reduce_topk_kernel<<<(ROWS + 255) / 256, 256, 0, stream>>>(part, scr);
  }
  image_max_kernel<<<BATCH, 256, 0, stream>>>(scr, out);
  upsample_kernel<<<(BATCH * OH * OW + 255) / 256, 256, 0, stream>>>(scr, out);
}

// Round 2
// 678.547 us; speedup vs baseline: 1.5687x; 1.5687x over previous
//
#include <hip/hip_runtime.h>
#include <stdint.h>

#define L_LAYERS 4
#define BATCH 8
#define PHH 24
#define PWW 24
#define PP (PHH*PWW)        // 576
#define DD 1024
#define ROWS (BATCH*PP)     // 4608
#define OH 336
#define OW 336
#define NTILES 72           // 4608/64  (64-col max groups)
#define TT 36               // 4608/128 (128x128 tiles per dim)
#define NPAIRS (TT*(TT+1)/2)  // 666 upper-triangle tiles

typedef __attribute__((ext_vector_type(8))) __bf16 bf16x8;
typedef __attribute__((ext_vector_type(4))) float f32x4;

// float -> bf16 round-to-nearest-even (raw bits)
__device__ __forceinline__ unsigned short f2bf(float f) {
  unsigned int u = __float_as_uint(f);
  unsigned int r = (u + 0x7FFFu + ((u >> 16) & 1u)) >> 16;
  return (unsigned short)r;
}

// async global->LDS, 16B per lane. LDS dest must be wave-uniform base + lane*16.
__device__ __forceinline__ void async16(const void* g, void* l) {
  __builtin_amdgcn_global_load_lds(
      (const __attribute__((address_space(1))) void*)(size_t)(uintptr_t)g,
      (__attribute__((address_space(3))) void*)(uint32_t)(uintptr_t)l,
      16, 0, 0);
}

// ---------------------------------------------------------------------------
// Kernel 1: avg-pool (rxr, zero-pad, SAME) + L2-normalize + cast to bf16.
// The /r^2 cancels under normalization, so we normalize the plain sum.
// ---------------------------------------------------------------------------
__global__ __launch_bounds__(256) void pool_norm_kernel(
    const float* __restrict__ feat,      // layer base: [BATCH][PP][DD]
    unsigned short* __restrict__ nf,     // [ROWS][DD] bf16 bits
    int r) {
  const int row = blockIdx.x;            // b*576 + p
  const int b = row / PP;
  const int p = row % PP;
  const int py = p / PWW, px = p % PWW;
  const int pad = r >> 1;
  const int t = threadIdx.x;
  const int d0 = t * 4;
  const float* base = feat + (size_t)b * PP * DD;

  float a0 = 0.f, a1 = 0.f, a2 = 0.f, a3 = 0.f;
  for (int dy = -pad; dy <= pad; ++dy) {
    int yy = py + dy; if (yy < 0 || yy >= PHH) continue;
    for (int dx = -pad; dx <= pad; ++dx) {
      int xx = px + dx; if (xx < 0 || xx >= PWW) continue;
      const float4 v = *(const float4*)(base + (size_t)(yy * PWW + xx) * DD + d0);
      a0 += v.x; a1 += v.y; a2 += v.z; a3 += v.w;
    }
  }
  float ss = a0*a0 + a1*a1 + a2*a2 + a3*a3;
  #pragma unroll
  for (int off = 32; off > 0; off >>= 1) ss += __shfl_down(ss, off);
  __shared__ float red[4];
  const int lane = t & 63, w = t >> 6;
  if (lane == 0) red[w] = ss;
  __syncthreads();
  const float tot = red[0] + red[1] + red[2] + red[3];
  const float rn = rsqrtf(tot);

  ushort4 o;
  o.x = f2bf(a0 * rn); o.y = f2bf(a1 * rn);
  o.z = f2bf(a2 * rn); o.w = f2bf(a3 * rn);
  *(ushort4*)(nf + (size_t)row * DD + d0) = o;
}

// ---------------------------------------------------------------------------
// Kernel 2: symmetric Gram GEMM, upper-triangle 128x128 tiles only.
// C = F F^T. For tile (it,jt), it<=jt: fused row-max over each 64-col group
// (written for rows of tile it) AND col-max over each 64-row group (written
// for rows(=cols) of tile jt, i.e. the transposed tile's row-max).
// Each (row, 64-group) slot of partialL has exactly one writer.
// 4 waves in 2x2 layout, 64x64 output each (4x4 frags of 16x16x32 bf16).
// XOR-swizzled LDS (conflict-free ds_read_b128 w/ global_load_lds staging).
// ---------------------------------------------------------------------------
__global__ __launch_bounds__(256, 3) void gemm_max_kernel(
    const unsigned short* __restrict__ nf,   // [ROWS][DD] bf16 bits
    float* __restrict__ partialL) {          // [ROWS][NTILES]
  __shared__ unsigned short As[128 * 64];
  __shared__ unsigned short Bs[128 * 64];

  const int t = threadIdx.x;
  const int lane = t & 63;
  const int wave = t >> 6;
  const int wm = wave >> 1;    // row half (64 rows)
  const int wn = wave & 1;     // col half (64 cols)

  // decode linear block id -> upper-triangle (it, jt), it <= jt
  int it = 0, rem = blockIdx.x;
  while (rem >= TT - it) { rem -= TT - it; ++it; }
  const int jt = it + rem;
  const int row0 = it * 128;
  const int col0 = jt * 128;

  const f32x4 zero = {0.f, 0.f, 0.f, 0.f};
  f32x4 acc[4][4];
  #pragma unroll
  for (int m = 0; m < 4; ++m)
    #pragma unroll
    for (int n = 0; n < 4; ++n) acc[m][n] = zero;

  const unsigned short* gA = nf + (size_t)row0 * DD;
  const unsigned short* gB = nf + (size_t)col0 * DD;

  for (int kt = 0; kt < DD / 64; ++kt) {
    const int k0 = kt * 64;
    // 128 rows x 64 K each = 1024 16B-chunks per matrix; chunk c: row=c>>3,
    // slot j=c&7 holds global k-chunk j ^ (row&7)  (XOR swizzle)
    #pragma unroll
    for (int i = 0; i < 4; ++i) {
      int c = i * 256 + t;
      int row = c >> 3, j = c & 7;
      int g = j ^ (row & 7);
      async16(gA + (size_t)row * DD + k0 + g * 8, &As[c * 8]);
    }
    #pragma unroll
    for (int i = 0; i < 4; ++i) {
      int c = i * 256 + t;
      int row = c >> 3, j = c & 7;
      int g = j ^ (row & 7);
      async16(gB + (size_t)row * DD + k0 + g * 8, &Bs[c * 8]);
    }
    __syncthreads();   // drains vmcnt (global_load_lds) + barrier
    #pragma unroll
    for (int s = 0; s < 2; ++s) {
      const int kc = s * 4 + (lane >> 4);   // 16B chunk index within 64-wide K
      bf16x8 af[4], bfr[4];
      #pragma unroll
      for (int m = 0; m < 4; ++m) {
        int row = wm * 64 + m * 16 + (lane & 15);
        af[m] = *(const bf16x8*)&As[row * 64 + ((kc ^ (row & 7)) << 3)];
      }
      #pragma unroll
      for (int n = 0; n < 4; ++n) {
        int brow = wn * 64 + n * 16 + (lane & 15);
        bfr[n] = *(const bf16x8*)&Bs[brow * 64 + ((kc ^ (brow & 7)) << 3)];
      }
      #pragma unroll
      for (int m = 0; m < 4; ++m)
        #pragma unroll
        for (int n = 0; n < 4; ++n)
          acc[m][n] = __builtin_amdgcn_mfma_f32_16x16x32_bf16(af[m], bfr[n], acc[m][n], 0, 0, 0);
    }
    __syncthreads();
  }

  // C/D layout: col = lane&15, row = (lane>>4)*4 + reg  [m89]
  // Row-max over this wave's 64 cols (= exactly one 64-col group 2*jt+wn).
  #pragma unroll
  for (int m = 0; m < 4; ++m) {
    #pragma unroll
    for (int g = 0; g < 4; ++g) {
      float v = fmaxf(fmaxf(acc[m][0][g], acc[m][1][g]),
                      fmaxf(acc[m][2][g], acc[m][3][g]));
      v = fmaxf(v, __shfl_xor(v, 1));
      v = fmaxf(v, __shfl_xor(v, 2));
      v = fmaxf(v, __shfl_xor(v, 4));
      v = fmaxf(v, __shfl_xor(v, 8));
      if ((lane & 15) == 0) {
        int row = row0 + wm * 64 + m * 16 + (lane >> 4) * 4 + g;
        partialL[(size_t)row * NTILES + 2 * jt + wn] = v;
      }
    }
  }
  // Col-max over this wave's 64 rows (= one 64-row group 2*it+wm), written as
  // the transposed tile's row-max. Skip on diagonal (identical values).
  if (it != jt) {
    #pragma unroll
    for (int n = 0; n < 4; ++n) {
      float v = -1e30f;
      #pragma unroll
      for (int m = 0; m < 4; ++m)
        #pragma unroll
        for (int g = 0; g < 4; ++g) v = fmaxf(v, acc[m][n][g]);
      v = fmaxf(v, __shfl_xor(v, 16));
      v = fmaxf(v, __shfl_xor(v, 32));
      if (lane < 16) {
        int col = col0 + wn * 64 + n * 16 + lane;
        partialL[(size_t)col * NTILES + 2 * it + wm] = v;
      }
    }
  }
}

// ---------------------------------------------------------------------------
// Kernel 3: per row: per layer, max over 9 q-tiles per image c, d-transform,
// top-2 smallest over c != b, accumulate into scores (summed over r and l).
// ---------------------------------------------------------------------------
__global__ __launch_bounds__(256) void reduce_topk_kernel(
    const float* __restrict__ partial,   // [L][ROWS][NTILES]
    float* __restrict__ scores) {        // [ROWS] accumulator
  const int row = blockIdx.x * 256 + threadIdx.x;
  if (row >= ROWS) return;
  const int b = row / PP;
  float sum = 0.f;
  for (int l = 0; l < L_LAYERS; ++l) {
    const float* pr = partial + ((size_t)l * ROWS + row) * NTILES;
    float d1 = 1e30f, d2 = 1e30f;
    #pragma unroll
    for (int c = 0; c < BATCH; ++c) {
      if (c == b) continue;
      float md = pr[c * 9];
      #pragma unroll
      for (int q = 1; q < 9; ++q) md = fmaxf(md, pr[c * 9 + q]);
      float d = sqrtf(fmaxf(2.f - 2.f * md, 0.f));
      if (d < d1) { d2 = d1; d1 = d; }
      else if (d < d2) { d2 = d; }
    }
    sum += 0.5f * (d1 + d2);
  }
  scores[row] += sum;
}

// ---------------------------------------------------------------------------
// Kernel 4: scores_image[b] = max_p scores[b,p] / 12
// ---------------------------------------------------------------------------
__global__ __launch_bounds__(256) void image_max_kernel(
    const float* __restrict__ scores, float* __restrict__ out) {
  const int b = blockIdx.x;
  const int t = threadIdx.x;
  float m = -1e30f;
  for (int p = t; p < PP; p += 256) m = fmaxf(m, scores[b * PP + p]);
  #pragma unroll
  for (int off = 32; off > 0; off >>= 1) m = fmaxf(m, __shfl_down(m, off));
  __shared__ float red[4];
  if ((t & 63) == 0) red[t >> 6] = m;
  __syncthreads();
  if (t == 0)
    out[b] = fmaxf(fmaxf(red[0], red[1]), fmaxf(red[2], red[3])) * (1.f / 12.f);
}

// ---------------------------------------------------------------------------
// Kernel 5: bilinear (align_corners) 24x24 -> 336x336, scale 1/12
// ---------------------------------------------------------------------------
__global__ __launch_bounds__(256) void upsample_kernel(
    const float* __restrict__ scores, float* __restrict__ out) {
  const int idx = blockIdx.x * 256 + threadIdx.x;
  if (idx >= BATCH * OH * OW) return;
  const int b = idx / (OH * OW);
  const int rem = idx % (OH * OW);
  const int y = rem / OW, x = rem % OW;
  const float sc = (float)(23.0 / 335.0);
  const float ys = y * sc, xs = x * sc;
  const int y0 = (int)floorf(ys), x0 = (int)floorf(xs);
  const float wy = ys - (float)y0, wx = xs - (float)x0;
  const int y1 = min(y0 + 1, PHH - 1), x1 = min(x0 + 1, PWW - 1);
  const float* sb = scores + b * PP;
  const float f00 = sb[y0 * PWW + x0], f01 = sb[y0 * PWW + x1];
  const float f10 = sb[y1 * PWW + x0], f11 = sb[y1 * PWW + x1];
  const float v = f00 * (1.f - wy) * (1.f - wx) + f01 * (1.f - wy) * wx +
                  f10 * wy * (1.f - wx) + f11 * wy * wx;
  out[8 + idx] = v * (1.f / 12.f);
}

// ---------------------------------------------------------------------------
extern "C" void kernel_launch(void* const* d_in, const int* in_sizes, int n_in,
                              void* d_out, int out_size, void* d_ws, size_t ws_size,
                              hipStream_t stream) {
  const float* feat = (const float*)d_in[0];     // [4][8][576][1024] f32
  float* out = (float*)d_out;                    // [8] ++ [8][336][336]
  char* ws = (char*)d_ws;

  // workspace layout (~14.8 MB)
  unsigned short* nf   = (unsigned short*)ws;                          // 9,437,184 B
  float*          part = (float*)(ws + 9437184);                       // 5,308,416 B
  float*          scr  = (float*)(ws + 9437184 + 5308416);             //    18,432 B

  hipMemsetAsync(scr, 0, ROWS * sizeof(float), stream);

  const int rlist[3] = {1, 3, 5};
  for (int ri = 0; ri < 3; ++ri) {
    const int r = rlist[ri];
    for (int l = 0; l < L_LAYERS; ++l) {
      pool_norm_kernel<<<ROWS, 256, 0, stream>>>(
          feat + (size_t)l * BATCH * PP * DD, nf, r);
      gemm_max_kernel<<<NPAIRS, 256, 0, stream>>>(
          nf, part + (size_t)l * ROWS * NTILES);
    }
    reduce_topk_kernel<<<(ROWS + 255) / 256, 256, 0, stream>>>(part, scr);
  }
  image_max_kernel<<<BATCH, 256, 0, stream>>>(scr, out);
  upsample_kernel<<<(BATCH * OH * OW + 255) / 256, 256, 0, stream>>>(scr, out);
}

// Round 3
// 506.031 us; speedup vs baseline: 2.1035x; 1.3409x over previous
//
#include <hip/hip_runtime.h>
#include <stdint.h>

#define L_LAYERS 4
#define BATCH 8
#define PHH 24
#define PWW 24
#define PP (PHH*PWW)        // 576
#define DD 1024
#define ROWS (BATCH*PP)     // 4608
#define OH 336
#define OW 336
#define NTILES 72           // 4608/64  (64-col max groups; 64 divides 576*? -> each group in one image)
#define TT 36               // 4608/128 (128x128 tiles per dim)
#define NPAIRS (TT*(TT+1)/2)  // 666 upper-triangle tiles
#define NCOMBO 12           // 3 radii x 4 layers

typedef __attribute__((ext_vector_type(8))) __bf16 bf16x8;
typedef __attribute__((ext_vector_type(4))) float f32x4;

// float -> bf16 round-to-nearest-even (raw bits)
__device__ __forceinline__ unsigned short f2bf(float f) {
  unsigned int u = __float_as_uint(f);
  unsigned int r = (u + 0x7FFFu + ((u >> 16) & 1u)) >> 16;
  return (unsigned short)r;
}

// async global->LDS, 16B per lane. LDS dest must be wave-uniform base + lane*16.
__device__ __forceinline__ void async16(const void* g, void* l) {
  __builtin_amdgcn_global_load_lds(
      (const __attribute__((address_space(1))) void*)(size_t)(uintptr_t)g,
      (__attribute__((address_space(3))) void*)(uint32_t)(uintptr_t)l,
      16, 0, 0);
}

// ---------------------------------------------------------------------------
// Kernel 1: fused avg-pool r=1,3,5 + L2-normalize + bf16 cast, all layers.
// 5x5 neighborhood loaded once, feeds all three pooled sums (the /r^2 cancels
// under normalization). grid = (ROWS, L_LAYERS).
// nf_all combo index = ri*L_LAYERS + l.
// ---------------------------------------------------------------------------
__global__ __launch_bounds__(256) void pool_norm_all_kernel(
    const float* __restrict__ feat,      // [L][BATCH][PP][DD]
    unsigned short* __restrict__ nf_all) // [NCOMBO][ROWS][DD] bf16 bits
{
  const int row = blockIdx.x;            // b*576 + p
  const int l = blockIdx.y;
  const int b = row / PP;
  const int p = row % PP;
  const int py = p / PWW, px = p % PWW;
  const int t = threadIdx.x;
  const int d0 = t * 4;
  const float* base = feat + ((size_t)l * BATCH + b) * PP * DD;

  float s1[4] = {0,0,0,0}, s3[4] = {0,0,0,0}, s5[4] = {0,0,0,0};
  #pragma unroll
  for (int dy = -2; dy <= 2; ++dy) {
    int yy = py + dy; if (yy < 0 || yy >= PHH) continue;
    #pragma unroll
    for (int dx = -2; dx <= 2; ++dx) {
      int xx = px + dx; if (xx < 0 || xx >= PWW) continue;
      const float4 v = *(const float4*)(base + (size_t)(yy * PWW + xx) * DD + d0);
      s5[0] += v.x; s5[1] += v.y; s5[2] += v.z; s5[3] += v.w;
      if (dy >= -1 && dy <= 1 && dx >= -1 && dx <= 1) {
        s3[0] += v.x; s3[1] += v.y; s3[2] += v.z; s3[3] += v.w;
        if (dy == 0 && dx == 0) {
          s1[0] += v.x; s1[1] += v.y; s1[2] += v.z; s1[3] += v.w;
        }
      }
    }
  }
  float q1 = s1[0]*s1[0]+s1[1]*s1[1]+s1[2]*s1[2]+s1[3]*s1[3];
  float q3 = s3[0]*s3[0]+s3[1]*s3[1]+s3[2]*s3[2]+s3[3]*s3[3];
  float q5 = s5[0]*s5[0]+s5[1]*s5[1]+s5[2]*s5[2]+s5[3]*s5[3];
  #pragma unroll
  for (int off = 32; off > 0; off >>= 1) {
    q1 += __shfl_down(q1, off);
    q3 += __shfl_down(q3, off);
    q5 += __shfl_down(q5, off);
  }
  __shared__ float red[3][4];
  const int lane = t & 63, w = t >> 6;
  if (lane == 0) { red[0][w] = q1; red[1][w] = q3; red[2][w] = q5; }
  __syncthreads();
  const float rn1 = rsqrtf(red[0][0] + red[0][1] + red[0][2] + red[0][3]);
  const float rn3 = rsqrtf(red[1][0] + red[1][1] + red[1][2] + red[1][3]);
  const float rn5 = rsqrtf(red[2][0] + red[2][1] + red[2][2] + red[2][3]);

  const size_t rowoff = (size_t)row * DD + d0;
  ushort4 o;
  o.x = f2bf(s1[0]*rn1); o.y = f2bf(s1[1]*rn1); o.z = f2bf(s1[2]*rn1); o.w = f2bf(s1[3]*rn1);
  *(ushort4*)(nf_all + (size_t)(0*L_LAYERS + l) * ROWS * DD + rowoff) = o;
  o.x = f2bf(s3[0]*rn3); o.y = f2bf(s3[1]*rn3); o.z = f2bf(s3[2]*rn3); o.w = f2bf(s3[3]*rn3);
  *(ushort4*)(nf_all + (size_t)(1*L_LAYERS + l) * ROWS * DD + rowoff) = o;
  o.x = f2bf(s5[0]*rn5); o.y = f2bf(s5[1]*rn5); o.z = f2bf(s5[2]*rn5); o.w = f2bf(s5[3]*rn5);
  *(ushort4*)(nf_all + (size_t)(2*L_LAYERS + l) * ROWS * DD + rowoff) = o;
}

// ---------------------------------------------------------------------------
// Kernel 2: symmetric Gram GEMM for ALL 12 combos in one dispatch.
// grid = (NPAIRS, NCOMBO). Upper-triangle 128x128 tiles; tile pairs where
// both tiles lie fully inside the SAME image are dead (c==b masked) -> exit.
// Fused row-max per 64-col group + col-max (transposed tile's row-max).
// ---------------------------------------------------------------------------
__global__ __launch_bounds__(256, 3) void gemm_max_kernel(
    const unsigned short* __restrict__ nf_all,  // [NCOMBO][ROWS][DD]
    float* __restrict__ part) {                 // [NCOMBO][ROWS][NTILES]
  // decode linear block id -> upper-triangle (it, jt), it <= jt
  int it = 0, rem = blockIdx.x;
  while (rem >= TT - it) { rem -= TT - it; ++it; }
  const int jt = it + rem;
  const int row0 = it * 128;
  const int col0 = jt * 128;

  // dead-tile check: both tiles fully inside the same image -> never read
  {
    const bool inA = (row0 / PP) == ((row0 + 127) / PP);
    const bool inB = (col0 / PP) == ((col0 + 127) / PP);
    if (inA && inB && (row0 / PP) == (col0 / PP)) return;
  }

  __shared__ unsigned short As[128 * 64];
  __shared__ unsigned short Bs[128 * 64];

  const int t = threadIdx.x;
  const int lane = t & 63;
  const int wave = t >> 6;
  const int wm = wave >> 1;    // row half (64 rows)
  const int wn = wave & 1;     // col half (64 cols)
  const int combo = blockIdx.y;

  const unsigned short* nf = nf_all + (size_t)combo * ROWS * DD;
  float* partialL = part + (size_t)combo * ROWS * NTILES;

  const f32x4 zero = {0.f, 0.f, 0.f, 0.f};
  f32x4 acc[4][4];
  #pragma unroll
  for (int m = 0; m < 4; ++m)
    #pragma unroll
    for (int n = 0; n < 4; ++n) acc[m][n] = zero;

  const unsigned short* gA = nf + (size_t)row0 * DD;
  const unsigned short* gB = nf + (size_t)col0 * DD;

  for (int kt = 0; kt < DD / 64; ++kt) {
    const int k0 = kt * 64;
    // 128 rows x 64 K each = 1024 16B-chunks per matrix; chunk c: row=c>>3,
    // slot j=c&7 holds global k-chunk j ^ (row&7)  (XOR swizzle)
    #pragma unroll
    for (int i = 0; i < 4; ++i) {
      int c = i * 256 + t;
      int row = c >> 3, j = c & 7;
      int g = j ^ (row & 7);
      async16(gA + (size_t)row * DD + k0 + g * 8, &As[c * 8]);
    }
    #pragma unroll
    for (int i = 0; i < 4; ++i) {
      int c = i * 256 + t;
      int row = c >> 3, j = c & 7;
      int g = j ^ (row & 7);
      async16(gB + (size_t)row * DD + k0 + g * 8, &Bs[c * 8]);
    }
    __syncthreads();   // drains vmcnt (global_load_lds) + barrier
    #pragma unroll
    for (int s = 0; s < 2; ++s) {
      const int kc = s * 4 + (lane >> 4);   // 16B chunk index within 64-wide K
      bf16x8 af[4], bfr[4];
      #pragma unroll
      for (int m = 0; m < 4; ++m) {
        int row = wm * 64 + m * 16 + (lane & 15);
        af[m] = *(const bf16x8*)&As[row * 64 + ((kc ^ (row & 7)) << 3)];
      }
      #pragma unroll
      for (int n = 0; n < 4; ++n) {
        int brow = wn * 64 + n * 16 + (lane & 15);
        bfr[n] = *(const bf16x8*)&Bs[brow * 64 + ((kc ^ (brow & 7)) << 3)];
      }
      #pragma unroll
      for (int m = 0; m < 4; ++m)
        #pragma unroll
        for (int n = 0; n < 4; ++n)
          acc[m][n] = __builtin_amdgcn_mfma_f32_16x16x32_bf16(af[m], bfr[n], acc[m][n], 0, 0, 0);
    }
    __syncthreads();
  }

  // C/D layout: col = lane&15, row = (lane>>4)*4 + reg  [m89]
  // Row-max over this wave's 64 cols (group 2*jt+wn).
  #pragma unroll
  for (int m = 0; m < 4; ++m) {
    #pragma unroll
    for (int g = 0; g < 4; ++g) {
      float v = fmaxf(fmaxf(acc[m][0][g], acc[m][1][g]),
                      fmaxf(acc[m][2][g], acc[m][3][g]));
      v = fmaxf(v, __shfl_xor(v, 1));
      v = fmaxf(v, __shfl_xor(v, 2));
      v = fmaxf(v, __shfl_xor(v, 4));
      v = fmaxf(v, __shfl_xor(v, 8));
      if ((lane & 15) == 0) {
        int row = row0 + wm * 64 + m * 16 + (lane >> 4) * 4 + g;
        partialL[(size_t)row * NTILES + 2 * jt + wn] = v;
      }
    }
  }
  // Col-max over this wave's 64 rows (group 2*it+wm), written transposed.
  if (it != jt) {
    #pragma unroll
    for (int n = 0; n < 4; ++n) {
      float v = -1e30f;
      #pragma unroll
      for (int m = 0; m < 4; ++m)
        #pragma unroll
        for (int g = 0; g < 4; ++g) v = fmaxf(v, acc[m][n][g]);
      v = fmaxf(v, __shfl_xor(v, 16));
      v = fmaxf(v, __shfl_xor(v, 32));
      if (lane < 16) {
        int col = col0 + wn * 64 + n * 16 + lane;
        partialL[(size_t)col * NTILES + 2 * it + wm] = v;
      }
    }
  }
}

// ---------------------------------------------------------------------------
// Kernel 3: per row: for each of 12 combos, max over 9 q-groups per image c,
// d-transform, top-2 smallest over c != b; sum over combos -> scores[row].
// ---------------------------------------------------------------------------
__global__ __launch_bounds__(256) void reduce_topk_kernel(
    const float* __restrict__ part,      // [NCOMBO][ROWS][NTILES]
    float* __restrict__ scores) {        // [ROWS]
  const int row = blockIdx.x * 256 + threadIdx.x;
  if (row >= ROWS) return;
  const int b = row / PP;
  float sum = 0.f;
  for (int k = 0; k < NCOMBO; ++k) {
    const float* pr = part + ((size_t)k * ROWS + row) * NTILES;
    float d1 = 1e30f, d2 = 1e30f;
    #pragma unroll
    for (int c = 0; c < BATCH; ++c) {
      if (c == b) continue;
      float md = pr[c * 9];
      #pragma unroll
      for (int q = 1; q < 9; ++q) md = fmaxf(md, pr[c * 9 + q]);
      float d = sqrtf(fmaxf(2.f - 2.f * md, 0.f));
      if (d < d1) { d2 = d1; d1 = d; }
      else if (d < d2) { d2 = d; }
    }
    sum += 0.5f * (d1 + d2);
  }
  scores[row] = sum;
}

// ---------------------------------------------------------------------------
// Kernel 4: scores_image[b] = max_p scores[b,p] / 12
// ---------------------------------------------------------------------------
__global__ __launch_bounds__(256) void image_max_kernel(
    const float* __restrict__ scores, float* __restrict__ out) {
  const int b = blockIdx.x;
  const int t = threadIdx.x;
  float m = -1e30f;
  for (int p = t; p < PP; p += 256) m = fmaxf(m, scores[b * PP + p]);
  #pragma unroll
  for (int off = 32; off > 0; off >>= 1) m = fmaxf(m, __shfl_down(m, off));
  __shared__ float red[4];
  if ((t & 63) == 0) red[t >> 6] = m;
  __syncthreads();
  if (t == 0)
    out[b] = fmaxf(fmaxf(red[0], red[1]), fmaxf(red[2], red[3])) * (1.f / 12.f);
}

// ---------------------------------------------------------------------------
// Kernel 5: bilinear (align_corners) 24x24 -> 336x336, scale 1/12
// ---------------------------------------------------------------------------
__global__ __launch_bounds__(256) void upsample_kernel(
    const float* __restrict__ scores, float* __restrict__ out) {
  const int idx = blockIdx.x * 256 + threadIdx.x;
  if (idx >= BATCH * OH * OW) return;
  const int b = idx / (OH * OW);
  const int rem = idx % (OH * OW);
  const int y = rem / OW, x = rem % OW;
  const float sc = (float)(23.0 / 335.0);
  const float ys = y * sc, xs = x * sc;
  const int y0 = (int)floorf(ys), x0 = (int)floorf(xs);
  const float wy = ys - (float)y0, wx = xs - (float)x0;
  const int y1 = min(y0 + 1, PHH - 1), x1 = min(x0 + 1, PWW - 1);
  const float* sb = scores + b * PP;
  const float f00 = sb[y0 * PWW + x0], f01 = sb[y0 * PWW + x1];
  const float f10 = sb[y1 * PWW + x0], f11 = sb[y1 * PWW + x1];
  const float v = f00 * (1.f - wy) * (1.f - wx) + f01 * (1.f - wy) * wx +
                  f10 * wy * (1.f - wx) + f11 * wy * wx;
  out[8 + idx] = v * (1.f / 12.f);
}

// ---------------------------------------------------------------------------
extern "C" void kernel_launch(void* const* d_in, const int* in_sizes, int n_in,
                              void* d_out, int out_size, void* d_ws, size_t ws_size,
                              hipStream_t stream) {
  const float* feat = (const float*)d_in[0];     // [4][8][576][1024] f32
  float* out = (float*)d_out;                    // [8] ++ [8][336][336]
  char* ws = (char*)d_ws;

  // workspace layout (~129.2 MB of ~302 MB)
  const size_t NF_BYTES   = (size_t)NCOMBO * ROWS * DD * 2;        // 113,246,208
  const size_t PART_BYTES = (size_t)NCOMBO * ROWS * NTILES * 4;    //  15,925,248
  unsigned short* nf_all = (unsigned short*)ws;
  float*          part   = (float*)(ws + NF_BYTES);
  float*          scr    = (float*)(ws + NF_BYTES + PART_BYTES);

  pool_norm_all_kernel<<<dim3(ROWS, L_LAYERS), 256, 0, stream>>>(feat, nf_all);
  gemm_max_kernel<<<dim3(NPAIRS, NCOMBO), 256, 0, stream>>>(nf_all, part);
  reduce_topk_kernel<<<(ROWS + 255) / 256, 256, 0, stream>>>(part, scr);
  image_max_kernel<<<BATCH, 256, 0, stream>>>(scr, out);
  upsample_kernel<<<(BATCH * OH * OW + 255) / 256, 256, 0, stream>>>(scr, out);
}